// Round 1
// baseline (1044.005 us; speedup 1.0000x reference)
//
#include <hip/hip_runtime.h>
#include <stdint.h>

// ---------------------------------------------------------------------------
// VQ-VAE quantizer: coarse bf16-MFMA nearest-code search + exact fp32 rescore,
// codebook-decoded MLP, gather epilogue with fused commitment loss.
//
// Sizes (fixed by the problem): M=B*T=16384 rows, D=1024, K=8192 codes, H=512.
// Outputs (flat f32): recon[16777216], indices-as-float[16384], loss[1].
// ---------------------------------------------------------------------------

#define MROWS  16384
#define DDIM   1024
#define KCODES 8192
#define HDIM   512

typedef __attribute__((ext_vector_type(4))) float  f32x4;
typedef __attribute__((ext_vector_type(8))) __bf16 bf16x8;

__device__ __forceinline__ unsigned short f2bf(float f) {
  uint32_t b = __float_as_uint(f);
  b += 0x7FFFu + ((b >> 16) & 1u);          // RNE
  return (unsigned short)(b >> 16);
}

// async global->LDS, 16B per lane. LDS dest is wave-uniform base + lane*16;
// our LDS layout is linear in tid so per-lane pointer base+tid*16 matches.
__device__ __forceinline__ void gload_lds16(const void* g, void* l) {
  __builtin_amdgcn_global_load_lds(
      (__attribute__((address_space(1))) void*)(uintptr_t)g,
      (__attribute__((address_space(3))) void*)(uint32_t)(uintptr_t)l,
      16, 0, 0);
}

__device__ __forceinline__ float waveReduceSum(float v) {
#pragma unroll
  for (int off = 32; off > 0; off >>= 1) v += __shfl_xor(v, off, 64);
  return v;
}

// ---------------------------------------------------------------------------
// K1: features f32 -> bf16 (vectorized, 4 elems/thread)
// ---------------------------------------------------------------------------
__global__ __launch_bounds__(256) void cvt_x_kernel(
    const float* __restrict__ in, unsigned short* __restrict__ o, int n4) {
  const int id = blockIdx.x * 256 + threadIdx.x;
  if (id >= n4) return;
  const float4 v = ((const float4*)in)[id];
  ushort4 u;
  u.x = f2bf(v.x); u.y = f2bf(v.y); u.z = f2bf(v.z); u.w = f2bf(v.w);
  ((ushort4*)o)[id] = u;
}

// ---------------------------------------------------------------------------
// K2: codebook f32 -> bf16 + per-row squared norm cn[k]
// ---------------------------------------------------------------------------
__global__ __launch_bounds__(256) void cvt_cb_cn_kernel(
    const float* __restrict__ cb, unsigned short* __restrict__ o,
    float* __restrict__ cn) {
  __shared__ float wsum[4];
  const int k = blockIdx.x, t = threadIdx.x;
  const float4 v = ((const float4*)(cb + (size_t)k * DDIM))[t];
  ushort4 u;
  u.x = f2bf(v.x); u.y = f2bf(v.y); u.z = f2bf(v.z); u.w = f2bf(v.w);
  ((ushort4*)(o + (size_t)k * DDIM))[t] = u;
  float p = v.x * v.x + v.y * v.y + v.z * v.z + v.w * v.w;
  p = waveReduceSum(p);
  if ((t & 63) == 0) wsum[t >> 6] = p;
  __syncthreads();
  if (t == 0) cn[k] = wsum[0] + wsum[1] + wsum[2] + wsum[3];
}

// ---------------------------------------------------------------------------
// K3: weight transpose f32 [R][C] -> bf16 [C][R] (writes coalesced)
// ---------------------------------------------------------------------------
__global__ __launch_bounds__(256) void transpose_w_kernel(
    const float* __restrict__ w, unsigned short* __restrict__ wt, int R, int C) {
  const int id = blockIdx.x * 256 + threadIdx.x;
  if (id >= R * C) return;
  const int c = id / R, r = id % R;
  wt[id] = f2bf(w[(size_t)r * C + c]);
}

// ---------------------------------------------------------------------------
// K4: coarse scores = cn[k] - 2 * (xb . cbb[k]) via bf16 MFMA 16x16x32.
// 128x128 tile, 4 waves (2x2), BK=32, global_load_lds(16B) staging (m97 style).
// Each block owns 128 rows x one K-quarter (2048 codes); per-lane top-2
// (f32 score, idx) trackers -> shuffle merge over 16 lanes -> LDS merge over
// the wave_n pair -> cand[row][quarter*2 + {0,1}] = (score bits, idx).
// ---------------------------------------------------------------------------
__global__ __launch_bounds__(256) void coarse_kernel(
    const unsigned short* __restrict__ xb,   // [MROWS][DDIM] bf16
    const unsigned short* __restrict__ cbb,  // [KCODES][DDIM] bf16
    const float* __restrict__ cn,            // [KCODES]
    uint32_t* __restrict__ cand)             // [MROWS][8][2]
{
  __shared__ unsigned short As[128 * 32];
  __shared__ unsigned short Bs[128 * 32];
  __shared__ float mrgS[4][64][2];
  __shared__ int   mrgI[4][64][2];

  const int tid = threadIdx.x;
  const int l = tid & 63, w = tid >> 6;
  const int lr = l & 15, lg = l >> 4;
  const int wm = w >> 1, wn = w & 1;

  const int row_blk = blockIdx.x >> 2;   // 0..127
  const int split   = blockIdx.x & 3;    // 0..3 (K-quarter)
  const int r0 = row_blk * 128;
  const int nbase = split * 2048;

  const int prow = tid >> 2;             // staging piece row
  const int pcol = (tid & 3) * 8;        // staging piece col (shorts)

  const size_t aoff0 = (size_t)(r0 + prow) * DDIM + pcol;
  const size_t aoff1 = aoff0 + (size_t)64 * DDIM;

  float s1[16], s2[16];
  int   i1[16], i2[16];
#pragma unroll
  for (int t = 0; t < 16; ++t) {
    s1[t] = __builtin_inff(); s2[t] = __builtin_inff();
    i1[t] = KCODES; i2[t] = KCODES;
  }

  for (int nc = 0; nc < 16; ++nc) {
    const int c0 = nbase + nc * 128;
    f32x4 acc[4][4];
#pragma unroll
    for (int mi = 0; mi < 4; ++mi)
#pragma unroll
      for (int ni = 0; ni < 4; ++ni) acc[mi][ni] = 0.0f;

    const size_t boff0 = (size_t)(c0 + prow) * DDIM + pcol;
    const size_t boff1 = boff0 + (size_t)64 * DDIM;

    for (int ks = 0; ks < 32; ++ks) {
      const int k0 = ks * 32;
      gload_lds16(xb + aoff0 + k0, &As[tid * 8]);
      gload_lds16(xb + aoff1 + k0, &As[2048 + tid * 8]);
      gload_lds16(cbb + boff0 + k0, &Bs[tid * 8]);
      gload_lds16(cbb + boff1 + k0, &Bs[2048 + tid * 8]);
      __syncthreads();

      bf16x8 af[4], bfv[4];
#pragma unroll
      for (int mi = 0; mi < 4; ++mi)
        af[mi] = *reinterpret_cast<const bf16x8*>(
            &As[(wm * 64 + mi * 16 + lr) * 32 + lg * 8]);
#pragma unroll
      for (int ni = 0; ni < 4; ++ni)
        bfv[ni] = *reinterpret_cast<const bf16x8*>(
            &Bs[(wn * 64 + ni * 16 + lr) * 32 + lg * 8]);
#pragma unroll
      for (int mi = 0; mi < 4; ++mi)
#pragma unroll
        for (int ni = 0; ni < 4; ++ni)
          acc[mi][ni] = __builtin_amdgcn_mfma_f32_16x16x32_bf16(
              af[mi], bfv[ni], acc[mi][ni], 0, 0, 0);
      __syncthreads();
    }

    // fold this 128-col chunk into the per-lane top-2 trackers
#pragma unroll
    for (int ni = 0; ni < 4; ++ni) {
      const int col = c0 + wn * 64 + ni * 16 + lr;
      const float cnv = cn[col];
#pragma unroll
      for (int mi = 0; mi < 4; ++mi) {
#pragma unroll
        for (int r = 0; r < 4; ++r) {
          const float s = fmaf(-2.0f, acc[mi][ni][r], cnv);
          const int ti = mi * 4 + r;
          const bool lt1 = s < s1[ti];
          const bool lt2 = s < s2[ti];
          s2[ti] = lt1 ? s1[ti] : (lt2 ? s   : s2[ti]);
          i2[ti] = lt1 ? i1[ti] : (lt2 ? col : i2[ti]);
          s1[ti] = lt1 ? s   : s1[ti];
          i1[ti] = lt1 ? col : i1[ti];
        }
      }
    }
  }

  // butterfly-merge the 16 lanes that share each row
#pragma unroll
  for (int off = 1; off < 16; off <<= 1) {
#pragma unroll
    for (int ti = 0; ti < 16; ++ti) {
      const float t1 = __shfl_xor(s1[ti], off, 64);
      const int   j1 = __shfl_xor(i1[ti], off, 64);
      const float t2 = __shfl_xor(s2[ti], off, 64);
      const int   j2 = __shfl_xor(i2[ti], off, 64);
      const bool c1 = t1 < s1[ti];
      const float w1s = c1 ? t1 : s1[ti]; const int w1i = c1 ? j1 : i1[ti];
      const float l1s = c1 ? s1[ti] : t1; const int l1i = c1 ? i1[ti] : j1;
      const bool c2 = t2 < s2[ti];
      const float m2s = c2 ? t2 : s2[ti]; const int m2i = c2 ? j2 : i2[ti];
      const bool c3 = m2s < l1s;
      s2[ti] = c3 ? m2s : l1s; i2[ti] = c3 ? m2i : l1i;
      s1[ti] = w1s;            i1[ti] = w1i;
    }
  }

  if (lr == 0) {
#pragma unroll
    for (int mi = 0; mi < 4; ++mi)
#pragma unroll
      for (int r = 0; r < 4; ++r) {
        const int r64 = mi * 16 + lg * 4 + r;
        mrgS[w][r64][0] = s1[mi * 4 + r]; mrgS[w][r64][1] = s2[mi * 4 + r];
        mrgI[w][r64][0] = i1[mi * 4 + r]; mrgI[w][r64][1] = i2[mi * 4 + r];
      }
  }
  __syncthreads();

  if (tid < 128) {
    const int wmm = tid >> 6, r64 = tid & 63;
    const float a1 = mrgS[wmm * 2][r64][0],     a2 = mrgS[wmm * 2][r64][1];
    const int   ia1 = mrgI[wmm * 2][r64][0],    ia2 = mrgI[wmm * 2][r64][1];
    const float b1 = mrgS[wmm * 2 + 1][r64][0], b2 = mrgS[wmm * 2 + 1][r64][1];
    const int   ib1 = mrgI[wmm * 2 + 1][r64][0], ib2 = mrgI[wmm * 2 + 1][r64][1];
    const bool c1 = b1 < a1;
    const float n1 = c1 ? b1 : a1; const int ni1 = c1 ? ib1 : ia1;
    const float lo = c1 ? a1 : b1; const int li  = c1 ? ia1 : ib1;
    const bool c2 = b2 < a2;
    const float m2 = c2 ? b2 : a2; const int mi2 = c2 ? ib2 : ia2;
    const bool c3 = m2 < lo;
    const float n2 = c3 ? m2 : lo; const int ni2 = c3 ? mi2 : li;
    const int grow = r0 + wmm * 64 + r64;
    uint32_t* cp = cand + ((size_t)grow * 8 + split * 2) * 2;
    cp[0] = __float_as_uint(n1); cp[1] = (uint32_t)ni1;
    cp[2] = __float_as_uint(n2); cp[3] = (uint32_t)ni2;
  }
}

// ---------------------------------------------------------------------------
// K5: exact fp32 rescore of <=8 candidates/row (skip those > min + 2.5 margin,
// ~15 sigma of coarse error). One wave per row. Writes idx (ws + out-as-f32)
// and zeroes the loss slot.
// ---------------------------------------------------------------------------
__global__ __launch_bounds__(64) void rescore_kernel(
    const float* __restrict__ x, const float* __restrict__ cb,
    const uint32_t* __restrict__ cand, int* __restrict__ idx_ws,
    float* __restrict__ out) {
  const int r = blockIdx.x;
  const int l = threadIdx.x;

  float cs[8]; int ci[8];
#pragma unroll
  for (int c = 0; c < 8; ++c) {
    cs[c] = __uint_as_float(cand[((size_t)r * 8 + c) * 2]);
    ci[c] = (int)cand[((size_t)r * 8 + c) * 2 + 1];
  }
  float smin = cs[0];
#pragma unroll
  for (int c = 1; c < 8; ++c) smin = fminf(smin, cs[c]);
  const float thresh = smin + 2.5f;

  const float4* x4 = (const float4*)(x + (size_t)r * DDIM);
  float4 xv[4];
#pragma unroll
  for (int i = 0; i < 4; ++i) xv[i] = x4[i * 64 + l];

  float bestS = __builtin_inff(); int bestI = KCODES;
  for (int c = 0; c < 8; ++c) {
    if (cs[c] > thresh) continue;               // wave-uniform branch
    const int code = ci[c];
    const float4* c4 = (const float4*)(cb + (size_t)code * DDIM);
    float dot = 0.f, nn = 0.f;
#pragma unroll
    for (int i = 0; i < 4; ++i) {
      const float4 cv = c4[i * 64 + l];
      dot = fmaf(xv[i].x, cv.x, dot); dot = fmaf(xv[i].y, cv.y, dot);
      dot = fmaf(xv[i].z, cv.z, dot); dot = fmaf(xv[i].w, cv.w, dot);
      nn  = fmaf(cv.x, cv.x, nn);     nn  = fmaf(cv.y, cv.y, nn);
      nn  = fmaf(cv.z, cv.z, nn);     nn  = fmaf(cv.w, cv.w, nn);
    }
#pragma unroll
    for (int off = 32; off > 0; off >>= 1) {
      dot += __shfl_xor(dot, off, 64);
      nn  += __shfl_xor(nn,  off, 64);
    }
    const float sc = nn - 2.0f * dot;
    if (sc < bestS || (sc == bestS && code < bestI)) { bestS = sc; bestI = code; }
  }
  if (l == 0) {
    idx_ws[r] = bestI;
    out[(size_t)MROWS * DDIM + r] = (float)bestI;
  }
  if (r == 0 && l == 0) out[(size_t)MROWS * DDIM + MROWS] = 0.0f;
}

// ---------------------------------------------------------------------------
// K6/K7: bf16 GEMM C = A[M][K] * B[N][K]^T (+bias, epilogue), m97-style tile.
// EPI==1: relu -> bf16 store (hidden). EPI==2: f32 store (decoded).
// ---------------------------------------------------------------------------
template <int EPI>
__global__ __launch_bounds__(256) void gemm_bt_kernel(
    const unsigned short* __restrict__ A, const unsigned short* __restrict__ B,
    const float* __restrict__ bias, void* __restrict__ outp,
    int Nsize, int Kred, int nblk) {
  __shared__ unsigned short As[128 * 32];
  __shared__ unsigned short Bs[128 * 32];
  const int tid = threadIdx.x;
  const int l = tid & 63, w = tid >> 6;
  const int lr = l & 15, lg = l >> 4;
  const int wm = w >> 1, wn = w & 1;
  const int mb = blockIdx.x / nblk, nb = blockIdx.x % nblk;
  const int r0 = mb * 128, c0 = nb * 128;
  const int prow = tid >> 2, pcol = (tid & 3) * 8;

  f32x4 acc[4][4];
#pragma unroll
  for (int mi = 0; mi < 4; ++mi)
#pragma unroll
    for (int ni = 0; ni < 4; ++ni) acc[mi][ni] = 0.0f;

  const size_t aoff0 = (size_t)(r0 + prow) * Kred + pcol;
  const size_t aoff1 = aoff0 + (size_t)64 * Kred;
  const size_t boff0 = (size_t)(c0 + prow) * Kred + pcol;
  const size_t boff1 = boff0 + (size_t)64 * Kred;

  const int nks = Kred >> 5;
  for (int ks = 0; ks < nks; ++ks) {
    const int k0 = ks * 32;
    gload_lds16(A + aoff0 + k0, &As[tid * 8]);
    gload_lds16(A + aoff1 + k0, &As[2048 + tid * 8]);
    gload_lds16(B + boff0 + k0, &Bs[tid * 8]);
    gload_lds16(B + boff1 + k0, &Bs[2048 + tid * 8]);
    __syncthreads();

    bf16x8 af[4], bfv[4];
#pragma unroll
    for (int mi = 0; mi < 4; ++mi)
      af[mi] = *reinterpret_cast<const bf16x8*>(
          &As[(wm * 64 + mi * 16 + lr) * 32 + lg * 8]);
#pragma unroll
    for (int ni = 0; ni < 4; ++ni)
      bfv[ni] = *reinterpret_cast<const bf16x8*>(
          &Bs[(wn * 64 + ni * 16 + lr) * 32 + lg * 8]);
#pragma unroll
    for (int mi = 0; mi < 4; ++mi)
#pragma unroll
      for (int ni = 0; ni < 4; ++ni)
        acc[mi][ni] = __builtin_amdgcn_mfma_f32_16x16x32_bf16(
            af[mi], bfv[ni], acc[mi][ni], 0, 0, 0);
    __syncthreads();
  }

#pragma unroll
  for (int ni = 0; ni < 4; ++ni) {
    const int col = c0 + wn * 64 + ni * 16 + lr;
    const float bv = bias[col];
#pragma unroll
    for (int mi = 0; mi < 4; ++mi) {
#pragma unroll
      for (int r = 0; r < 4; ++r) {
        const int row = r0 + wm * 64 + mi * 16 + lg * 4 + r;
        const float v = acc[mi][ni][r] + bv;
        if (EPI == 1) {
          ((unsigned short*)outp)[(size_t)row * Nsize + col] =
              f2bf(fmaxf(v, 0.0f));
        } else {
          ((float*)outp)[(size_t)row * Nsize + col] = v;
        }
      }
    }
  }
}

// ---------------------------------------------------------------------------
// K8: recon[row] = dec[idx[row]] gather-write + fused commitment loss.
// ---------------------------------------------------------------------------
__global__ __launch_bounds__(256) void epilogue_kernel(
    const float* __restrict__ x, const float* __restrict__ cb,
    const float* __restrict__ dec, const int* __restrict__ idx_ws,
    float* __restrict__ out) {
  __shared__ float wsum[4];
  const int r = blockIdx.x, t = threadIdx.x;
  const int code = idx_ws[r];
  const float4 dv = ((const float4*)(dec + (size_t)code * DDIM))[t];
  ((float4*)(out + (size_t)r * DDIM))[t] = dv;
  const float4 xv = ((const float4*)(x + (size_t)r * DDIM))[t];
  const float4 cv = ((const float4*)(cb + (size_t)code * DDIM))[t];
  const float ex = xv.x - cv.x, ey = xv.y - cv.y;
  const float ez = xv.z - cv.z, ew = xv.w - cv.w;
  float p = ex * ex + ey * ey + ez * ez + ew * ew;
  p = waveReduceSum(p);
  if ((t & 63) == 0) wsum[t >> 6] = p;
  __syncthreads();
  if (t == 0) {
    const float total = wsum[0] + wsum[1] + wsum[2] + wsum[3];
    // 0.25f / 16777216 is a power-of-two scale: exact
    atomicAdd(out + (size_t)MROWS * DDIM + MROWS, total * (0.25f / 16777216.0f));
  }
}

// ---------------------------------------------------------------------------
extern "C" void kernel_launch(void* const* d_in, const int* in_sizes, int n_in,
                              void* d_out, int out_size, void* d_ws,
                              size_t ws_size, hipStream_t stream) {
  const float* features = (const float*)d_in[0];  // [8,2048,1024]
  const float* codebook = (const float*)d_in[1];  // [8192,1024]
  const float* w1 = (const float*)d_in[2];        // [1024,512]
  const float* b1 = (const float*)d_in[3];        // [512]
  const float* w2 = (const float*)d_in[4];        // [512,1024]
  const float* b2 = (const float*)d_in[5];        // [1024]
  float* out = (float*)d_out;
  char* ws = (char*)d_ws;

  // workspace layout (bytes), total ~91.1 MB
  unsigned short* xb  = (unsigned short*)(ws + 0);         // 33,554,432
  unsigned short* cbb = (unsigned short*)(ws + 33554432);  // 16,777,216
  float*          cn  = (float*)(ws + 50331648);           //     32,768
  unsigned short* w1t = (unsigned short*)(ws + 50364416);  //  1,048,576
  unsigned short* w2t = (unsigned short*)(ws + 51412992);  //  1,048,576
  unsigned short* hb  = (unsigned short*)(ws + 52461568);  //  8,388,608
  float*          dec = (float*)(ws + 60850176);           // 33,554,432
  uint32_t*       cand = (uint32_t*)(ws + 94404608);       //  1,048,576
  int*            idxw = (int*)(ws + 95453184);            //     65,536

  cvt_x_kernel<<<16384, 256, 0, stream>>>(features, xb, MROWS * DDIM / 4);
  cvt_cb_cn_kernel<<<KCODES, 256, 0, stream>>>(codebook, cbb, cn);
  transpose_w_kernel<<<2048, 256, 0, stream>>>(w1, w1t, DDIM, HDIM);
  transpose_w_kernel<<<2048, 256, 0, stream>>>(w2, w2t, HDIM, DDIM);

  coarse_kernel<<<512, 256, 0, stream>>>(xb, cbb, cn, cand);
  rescore_kernel<<<MROWS, 64, 0, stream>>>(features, codebook, cand, idxw, out);

  // decode the codebook (8192 rows), then recon = dec[idx]
  gemm_bt_kernel<1><<<64 * (HDIM / 128), 256, 0, stream>>>(
      cbb, w1t, b1, hb, HDIM, DDIM, HDIM / 128);
  gemm_bt_kernel<2><<<64 * (DDIM / 128), 256, 0, stream>>>(
      hb, w2t, b2, dec, DDIM, HDIM, DDIM / 128);

  epilogue_kernel<<<MROWS, 256, 0, stream>>>(features, codebook, dec, idxw, out);
}

// Round 2
// 792.030 us; speedup vs baseline: 1.3181x; 1.3181x over previous
//
#include <hip/hip_runtime.h>
#include <stdint.h>

// ---------------------------------------------------------------------------
// VQ-VAE quantizer: coarse bf16-MFMA nearest-code search (full-grid 128x128
// tiles, m97 structure) + top-8 merge + exact fp32 rescore (fast path),
// codebook-decoded MLP, gather epilogue with fused commitment loss.
//
// Sizes: M=B*T=16384 rows, D=1024, K=8192 codes, H=512.
// Outputs (flat f32): recon[16777216], indices-as-float[16384], loss[1].
// ---------------------------------------------------------------------------

#define MROWS  16384
#define DDIM   1024
#define KCODES 8192
#define HDIM   512

typedef __attribute__((ext_vector_type(4))) float  f32x4;
typedef __attribute__((ext_vector_type(8))) __bf16 bf16x8;

__device__ __forceinline__ unsigned short f2bf(float f) {
  uint32_t b = __float_as_uint(f);
  b += 0x7FFFu + ((b >> 16) & 1u);          // RNE
  return (unsigned short)(b >> 16);
}

__device__ __forceinline__ void gload_lds16(const void* g, void* l) {
  __builtin_amdgcn_global_load_lds(
      (__attribute__((address_space(1))) void*)(uintptr_t)g,
      (__attribute__((address_space(3))) void*)(uint32_t)(uintptr_t)l,
      16, 0, 0);
}

__device__ __forceinline__ float waveReduceSum(float v) {
#pragma unroll
  for (int off = 32; off > 0; off >>= 1) v += __shfl_xor(v, off, 64);
  return v;
}

// ---------------------------------------------------------------------------
// K1: features f32 -> bf16
// ---------------------------------------------------------------------------
__global__ __launch_bounds__(256) void cvt_x_kernel(
    const float* __restrict__ in, unsigned short* __restrict__ o, int n4) {
  const int id = blockIdx.x * 256 + threadIdx.x;
  if (id >= n4) return;
  const float4 v = ((const float4*)in)[id];
  ushort4 u;
  u.x = f2bf(v.x); u.y = f2bf(v.y); u.z = f2bf(v.z); u.w = f2bf(v.w);
  ((ushort4*)o)[id] = u;
}

// ---------------------------------------------------------------------------
// K2: codebook f32 -> bf16 + per-row squared norm cn[k]
// ---------------------------------------------------------------------------
__global__ __launch_bounds__(256) void cvt_cb_cn_kernel(
    const float* __restrict__ cb, unsigned short* __restrict__ o,
    float* __restrict__ cn) {
  __shared__ float wsum[4];
  const int k = blockIdx.x, t = threadIdx.x;
  const float4 v = ((const float4*)(cb + (size_t)k * DDIM))[t];
  ushort4 u;
  u.x = f2bf(v.x); u.y = f2bf(v.y); u.z = f2bf(v.z); u.w = f2bf(v.w);
  ((ushort4*)(o + (size_t)k * DDIM))[t] = u;
  float p = v.x * v.x + v.y * v.y + v.z * v.z + v.w * v.w;
  p = waveReduceSum(p);
  if ((t & 63) == 0) wsum[t >> 6] = p;
  __syncthreads();
  if (t == 0) cn[k] = wsum[0] + wsum[1] + wsum[2] + wsum[3];
}

// ---------------------------------------------------------------------------
// K3: weight transpose f32 [R][C] -> bf16 [C][R]
// ---------------------------------------------------------------------------
__global__ __launch_bounds__(256) void transpose_w_kernel(
    const float* __restrict__ w, unsigned short* __restrict__ wt, int R, int C) {
  const int id = blockIdx.x * 256 + threadIdx.x;
  if (id >= R * C) return;
  const int c = id / R, r = id % R;
  wt[id] = f2bf(w[(size_t)r * C + c]);
}

// ---------------------------------------------------------------------------
// K4: coarse scores = cn[k] - 2 * (xb . cbb[k]) via bf16 MFMA 16x16x32.
// Full grid: (M/128)*(K/128) = 8192 blocks, 128x128 tile, 4 waves, BK=32,
// 32 K-steps. Per-row top-2 over the block's 128 cols folded ONCE at the end:
// per-lane trackers -> 16-lane butterfly -> LDS merge across the wn pair.
// Output cand2[row][colblk] = 2 x (score bits, idx).
// ---------------------------------------------------------------------------
__global__ __launch_bounds__(256) void coarse_kernel(
    const unsigned short* __restrict__ xb,   // [MROWS][DDIM] bf16
    const unsigned short* __restrict__ cbb,  // [KCODES][DDIM] bf16
    const float* __restrict__ cn,            // [KCODES]
    uint32_t* __restrict__ cand2)            // [MROWS][64][2][2]
{
  __shared__ unsigned short As[128 * 32];
  __shared__ unsigned short Bs[128 * 32];
  __shared__ float mrgS[4][64][2];
  __shared__ int   mrgI[4][64][2];

  const int tid = threadIdx.x;
  const int l = tid & 63, w = tid >> 6;
  const int lr = l & 15, lg = l >> 4;
  const int wm = w >> 1, wn = w & 1;

  // bijective XCD swizzle (nwg = 8192 = 8 * 1024)
  const int bid = blockIdx.x;
  const int swz = (bid & 7) * 1024 + (bid >> 3);
  const int mb = swz >> 6;     // 0..127
  const int nb = swz & 63;     // 0..63
  const int r0 = mb * 128;
  const int c0 = nb * 128;

  const int prow = tid >> 2;
  const int pcol = (tid & 3) * 8;

  const size_t aoff0 = (size_t)(r0 + prow) * DDIM + pcol;
  const size_t aoff1 = aoff0 + (size_t)64 * DDIM;
  const size_t boff0 = (size_t)(c0 + prow) * DDIM + pcol;
  const size_t boff1 = boff0 + (size_t)64 * DDIM;

  f32x4 acc[4][4];
#pragma unroll
  for (int mi = 0; mi < 4; ++mi)
#pragma unroll
    for (int ni = 0; ni < 4; ++ni) acc[mi][ni] = 0.0f;

  for (int ks = 0; ks < 32; ++ks) {
    const int k0 = ks * 32;
    gload_lds16(xb + aoff0 + k0, &As[tid * 8]);
    gload_lds16(xb + aoff1 + k0, &As[2048 + tid * 8]);
    gload_lds16(cbb + boff0 + k0, &Bs[tid * 8]);
    gload_lds16(cbb + boff1 + k0, &Bs[2048 + tid * 8]);
    __syncthreads();

    bf16x8 af[4], bfv[4];
#pragma unroll
    for (int mi = 0; mi < 4; ++mi)
      af[mi] = *reinterpret_cast<const bf16x8*>(
          &As[(wm * 64 + mi * 16 + lr) * 32 + lg * 8]);
#pragma unroll
    for (int ni = 0; ni < 4; ++ni)
      bfv[ni] = *reinterpret_cast<const bf16x8*>(
          &Bs[(wn * 64 + ni * 16 + lr) * 32 + lg * 8]);
#pragma unroll
    for (int mi = 0; mi < 4; ++mi)
#pragma unroll
      for (int ni = 0; ni < 4; ++ni)
        acc[mi][ni] = __builtin_amdgcn_mfma_f32_16x16x32_bf16(
            af[mi], bfv[ni], acc[mi][ni], 0, 0, 0);
    __syncthreads();
  }

  // per-lane top-2 trackers over the 4 ni columns (16 row-trackers)
  float s1[16], s2[16];
  int   i1[16], i2[16];
#pragma unroll
  for (int t = 0; t < 16; ++t) {
    s1[t] = __builtin_inff(); s2[t] = __builtin_inff();
    i1[t] = KCODES; i2[t] = KCODES;
  }
#pragma unroll
  for (int ni = 0; ni < 4; ++ni) {
    const int col = c0 + wn * 64 + ni * 16 + lr;
    const float cnv = cn[col];
#pragma unroll
    for (int mi = 0; mi < 4; ++mi) {
#pragma unroll
      for (int r = 0; r < 4; ++r) {
        const float s = fmaf(-2.0f, acc[mi][ni][r], cnv);
        const int ti = mi * 4 + r;
        const bool lt1 = s < s1[ti];
        const bool lt2 = s < s2[ti];
        s2[ti] = lt1 ? s1[ti] : (lt2 ? s   : s2[ti]);
        i2[ti] = lt1 ? i1[ti] : (lt2 ? col : i2[ti]);
        s1[ti] = lt1 ? s   : s1[ti];
        i1[ti] = lt1 ? col : i1[ti];
      }
    }
  }

  // butterfly-merge the 16 lanes sharing each row
#pragma unroll
  for (int off = 1; off < 16; off <<= 1) {
#pragma unroll
    for (int ti = 0; ti < 16; ++ti) {
      const float t1 = __shfl_xor(s1[ti], off, 64);
      const int   j1 = __shfl_xor(i1[ti], off, 64);
      const float t2 = __shfl_xor(s2[ti], off, 64);
      const int   j2 = __shfl_xor(i2[ti], off, 64);
      const bool c1 = t1 < s1[ti];
      const float w1s = c1 ? t1 : s1[ti]; const int w1i = c1 ? j1 : i1[ti];
      const float l1s = c1 ? s1[ti] : t1; const int l1i = c1 ? i1[ti] : j1;
      const bool c2 = t2 < s2[ti];
      const float m2s = c2 ? t2 : s2[ti]; const int m2i = c2 ? j2 : i2[ti];
      const bool c3 = m2s < l1s;
      s2[ti] = c3 ? m2s : l1s; i2[ti] = c3 ? m2i : l1i;
      s1[ti] = w1s;            i1[ti] = w1i;
    }
  }

  if (lr == 0) {
#pragma unroll
    for (int mi = 0; mi < 4; ++mi)
#pragma unroll
      for (int r = 0; r < 4; ++r) {
        const int r64 = mi * 16 + lg * 4 + r;
        mrgS[w][r64][0] = s1[mi * 4 + r]; mrgS[w][r64][1] = s2[mi * 4 + r];
        mrgI[w][r64][0] = i1[mi * 4 + r]; mrgI[w][r64][1] = i2[mi * 4 + r];
      }
  }
  __syncthreads();

  if (tid < 128) {
    const int wmm = tid >> 6, r64 = tid & 63;
    const float a1 = mrgS[wmm * 2][r64][0],     a2 = mrgS[wmm * 2][r64][1];
    const int   ia1 = mrgI[wmm * 2][r64][0],    ia2 = mrgI[wmm * 2][r64][1];
    const float b1 = mrgS[wmm * 2 + 1][r64][0], b2 = mrgS[wmm * 2 + 1][r64][1];
    const int   ib1 = mrgI[wmm * 2 + 1][r64][0], ib2 = mrgI[wmm * 2 + 1][r64][1];
    const bool c1 = b1 < a1;
    const float n1 = c1 ? b1 : a1; const int ni1 = c1 ? ib1 : ia1;
    const float lo = c1 ? a1 : b1; const int li  = c1 ? ia1 : ib1;
    const bool c2 = b2 < a2;
    const float m2 = c2 ? b2 : a2; const int mi2 = c2 ? ib2 : ia2;
    const bool c3 = m2 < lo;
    const float n2 = c3 ? m2 : lo; const int ni2 = c3 ? mi2 : li;
    const int grow = r0 + wmm * 64 + r64;
    uint4 o;
    o.x = __float_as_uint(n1); o.y = (uint32_t)ni1;
    o.z = __float_as_uint(n2); o.w = (uint32_t)ni2;
    *((uint4*)(cand2 + ((size_t)grow * 64 + nb) * 4)) = o;
  }
}

// ---------------------------------------------------------------------------
// K4b: per-row top-8 of the 128 (score,idx) block candidates.
// 4 rows per block (1 wave each); lane l holds colblk l's 2 pairs.
// ---------------------------------------------------------------------------
__global__ __launch_bounds__(256) void merge_kernel(
    const uint32_t* __restrict__ cand2, uint32_t* __restrict__ cand) {
  const int row = blockIdx.x * 4 + (threadIdx.x >> 6);
  const int l = threadIdx.x & 63;
  const uint4 v = ((const uint4*)(cand2 + (size_t)row * 256))[l];
  float sA = __uint_as_float(v.x); int iA = (int)v.y;
  float sB = __uint_as_float(v.z); int iB = (int)v.w;
  uint32_t* cp = cand + (size_t)row * 16;
#pragma unroll
  for (int t = 0; t < 8; ++t) {
    float bm; int bi;
    if (sA < sB || (sA == sB && iA < iB)) { bm = sA; bi = iA; }
    else                                  { bm = sB; bi = iB; }
#pragma unroll
    for (int off = 1; off < 64; off <<= 1) {
      const float os = __shfl_xor(bm, off, 64);
      const int   oi = __shfl_xor(bi, off, 64);
      if (os < bm || (os == bm && oi < bi)) { bm = os; bi = oi; }
    }
    if (l == 0) { cp[t * 2] = __float_as_uint(bm); cp[t * 2 + 1] = (uint32_t)bi; }
    if (iA == bi) { sA = __builtin_inff(); iA = 0x7FFFFFFF; }
    if (iB == bi) { sB = __builtin_inff(); iB = 0x7FFFFFFF; }
  }
}

// ---------------------------------------------------------------------------
// K5: exact fp32 rescore of candidates within coarse margin. Fast path: if
// only one candidate is within min+2.5 (typical: gap1->2 ~ 24 >> margin),
// the coarse argmin is exact -- skip the fp32 dot entirely.
// ---------------------------------------------------------------------------
__global__ __launch_bounds__(64) void rescore_kernel(
    const float* __restrict__ x, const float* __restrict__ cb,
    const uint32_t* __restrict__ cand, int* __restrict__ idx_ws,
    float* __restrict__ out) {
  const int r = blockIdx.x;
  const int l = threadIdx.x;
  if (r == 0 && l == 0) out[(size_t)MROWS * DDIM + MROWS] = 0.0f;

  float cs[8]; int ci[8];
#pragma unroll
  for (int c = 0; c < 8; ++c) {
    cs[c] = __uint_as_float(cand[((size_t)r * 8 + c) * 2]);
    ci[c] = (int)cand[((size_t)r * 8 + c) * 2 + 1];
  }
  float smin = cs[0]; int simin = ci[0];
#pragma unroll
  for (int c = 1; c < 8; ++c)
    if (cs[c] < smin || (cs[c] == smin && ci[c] < simin)) { smin = cs[c]; simin = ci[c]; }
  const float thresh = smin + 2.5f;
  int cnt = 0;
#pragma unroll
  for (int c = 0; c < 8; ++c) cnt += (cs[c] <= thresh) ? 1 : 0;

  if (cnt == 1) {
    if (l == 0) {
      idx_ws[r] = simin;
      out[(size_t)MROWS * DDIM + r] = (float)simin;
    }
    return;
  }

  const float4* x4 = (const float4*)(x + (size_t)r * DDIM);
  float4 xv[4];
#pragma unroll
  for (int i = 0; i < 4; ++i) xv[i] = x4[i * 64 + l];

  float bestS = __builtin_inff(); int bestI = KCODES;
  for (int c = 0; c < 8; ++c) {
    if (cs[c] > thresh) continue;               // wave-uniform branch
    const int code = ci[c];
    const float4* c4 = (const float4*)(cb + (size_t)code * DDIM);
    float dot = 0.f, nn = 0.f;
#pragma unroll
    for (int i = 0; i < 4; ++i) {
      const float4 cv = c4[i * 64 + l];
      dot = fmaf(xv[i].x, cv.x, dot); dot = fmaf(xv[i].y, cv.y, dot);
      dot = fmaf(xv[i].z, cv.z, dot); dot = fmaf(xv[i].w, cv.w, dot);
      nn  = fmaf(cv.x, cv.x, nn);     nn  = fmaf(cv.y, cv.y, nn);
      nn  = fmaf(cv.z, cv.z, nn);     nn  = fmaf(cv.w, cv.w, nn);
    }
#pragma unroll
    for (int off = 32; off > 0; off >>= 1) {
      dot += __shfl_xor(dot, off, 64);
      nn  += __shfl_xor(nn,  off, 64);
    }
    const float sc = nn - 2.0f * dot;
    if (sc < bestS || (sc == bestS && code < bestI)) { bestS = sc; bestI = code; }
  }
  if (l == 0) {
    idx_ws[r] = bestI;
    out[(size_t)MROWS * DDIM + r] = (float)bestI;
  }
}

// ---------------------------------------------------------------------------
// K6/K7: bf16 GEMM C = A[M][K] * B[N][K]^T (+bias). EPI==1: relu->bf16.
// EPI==2: f32 store.
// ---------------------------------------------------------------------------
template <int EPI>
__global__ __launch_bounds__(256) void gemm_bt_kernel(
    const unsigned short* __restrict__ A, const unsigned short* __restrict__ B,
    const float* __restrict__ bias, void* __restrict__ outp,
    int Nsize, int Kred, int nblk) {
  __shared__ unsigned short As[128 * 32];
  __shared__ unsigned short Bs[128 * 32];
  const int tid = threadIdx.x;
  const int l = tid & 63, w = tid >> 6;
  const int lr = l & 15, lg = l >> 4;
  const int wm = w >> 1, wn = w & 1;
  const int mb = blockIdx.x / nblk, nb = blockIdx.x % nblk;
  const int r0 = mb * 128, c0 = nb * 128;
  const int prow = tid >> 2, pcol = (tid & 3) * 8;

  f32x4 acc[4][4];
#pragma unroll
  for (int mi = 0; mi < 4; ++mi)
#pragma unroll
    for (int ni = 0; ni < 4; ++ni) acc[mi][ni] = 0.0f;

  const size_t aoff0 = (size_t)(r0 + prow) * Kred + pcol;
  const size_t aoff1 = aoff0 + (size_t)64 * Kred;
  const size_t boff0 = (size_t)(c0 + prow) * Kred + pcol;
  const size_t boff1 = boff0 + (size_t)64 * Kred;

  const int nks = Kred >> 5;
  for (int ks = 0; ks < nks; ++ks) {
    const int k0 = ks * 32;
    gload_lds16(A + aoff0 + k0, &As[tid * 8]);
    gload_lds16(A + aoff1 + k0, &As[2048 + tid * 8]);
    gload_lds16(B + boff0 + k0, &Bs[tid * 8]);
    gload_lds16(B + boff1 + k0, &Bs[2048 + tid * 8]);
    __syncthreads();

    bf16x8 af[4], bfv[4];
#pragma unroll
    for (int mi = 0; mi < 4; ++mi)
      af[mi] = *reinterpret_cast<const bf16x8*>(
          &As[(wm * 64 + mi * 16 + lr) * 32 + lg * 8]);
#pragma unroll
    for (int ni = 0; ni < 4; ++ni)
      bfv[ni] = *reinterpret_cast<const bf16x8*>(
          &Bs[(wn * 64 + ni * 16 + lr) * 32 + lg * 8]);
#pragma unroll
    for (int mi = 0; mi < 4; ++mi)
#pragma unroll
      for (int ni = 0; ni < 4; ++ni)
        acc[mi][ni] = __builtin_amdgcn_mfma_f32_16x16x32_bf16(
            af[mi], bfv[ni], acc[mi][ni], 0, 0, 0);
    __syncthreads();
  }

#pragma unroll
  for (int ni = 0; ni < 4; ++ni) {
    const int col = c0 + wn * 64 + ni * 16 + lr;
    const float bv = bias[col];
#pragma unroll
    for (int mi = 0; mi < 4; ++mi) {
#pragma unroll
      for (int r = 0; r < 4; ++r) {
        const int row = r0 + wm * 64 + mi * 16 + lg * 4 + r;
        const float v = acc[mi][ni][r] + bv;
        if (EPI == 1) {
          ((unsigned short*)outp)[(size_t)row * Nsize + col] =
              f2bf(fmaxf(v, 0.0f));
        } else {
          ((float*)outp)[(size_t)row * Nsize + col] = v;
        }
      }
    }
  }
}

// ---------------------------------------------------------------------------
// K8: recon[row] = dec[idx[row]] gather-write + fused commitment loss.
// ---------------------------------------------------------------------------
__global__ __launch_bounds__(256) void epilogue_kernel(
    const float* __restrict__ x, const float* __restrict__ cb,
    const float* __restrict__ dec, const int* __restrict__ idx_ws,
    float* __restrict__ out) {
  __shared__ float wsum[4];
  const int r = blockIdx.x, t = threadIdx.x;
  const int code = idx_ws[r];
  const float4 dv = ((const float4*)(dec + (size_t)code * DDIM))[t];
  ((float4*)(out + (size_t)r * DDIM))[t] = dv;
  const float4 xv = ((const float4*)(x + (size_t)r * DDIM))[t];
  const float4 cv = ((const float4*)(cb + (size_t)code * DDIM))[t];
  const float ex = xv.x - cv.x, ey = xv.y - cv.y;
  const float ez = xv.z - cv.z, ew = xv.w - cv.w;
  float p = ex * ex + ey * ey + ez * ez + ew * ew;
  p = waveReduceSum(p);
  if ((t & 63) == 0) wsum[t >> 6] = p;
  __syncthreads();
  if (t == 0) {
    const float total = wsum[0] + wsum[1] + wsum[2] + wsum[3];
    atomicAdd(out + (size_t)MROWS * DDIM + MROWS, total * (0.25f / 16777216.0f));
  }
}

// ---------------------------------------------------------------------------
extern "C" void kernel_launch(void* const* d_in, const int* in_sizes, int n_in,
                              void* d_out, int out_size, void* d_ws,
                              size_t ws_size, hipStream_t stream) {
  const float* features = (const float*)d_in[0];  // [8,2048,1024]
  const float* codebook = (const float*)d_in[1];  // [8192,1024]
  const float* w1 = (const float*)d_in[2];        // [1024,512]
  const float* b1 = (const float*)d_in[3];        // [512]
  const float* w2 = (const float*)d_in[4];        // [512,1024]
  const float* b2 = (const float*)d_in[5];        // [1024]
  float* out = (float*)d_out;
  char* ws = (char*)d_ws;

  // workspace layout (bytes), ~95.5 MB total.
  unsigned short* xb  = (unsigned short*)(ws + 0);         // 33,554,432
  unsigned short* cbb = (unsigned short*)(ws + 33554432);  // 16,777,216
  float*          cn  = (float*)(ws + 50331648);           //     32,768
  unsigned short* w1t = (unsigned short*)(ws + 50364416);  //  1,048,576
  unsigned short* w2t = (unsigned short*)(ws + 51412992);  //  1,048,576
  unsigned short* hb  = (unsigned short*)(ws + 52461568);  //  8,388,608
  float*          dec = (float*)(ws + 60850176);           // 33,554,432
  uint32_t*       cand = (uint32_t*)(ws + 94404608);       //  1,048,576
  int*            idxw = (int*)(ws + 95453184);            //     65,536
  // cand2 (16 MB) aliases dec: consumed by merge_kernel BEFORE gemm<2>
  // writes dec (stream-ordered -> safe).
  uint32_t*       cand2 = (uint32_t*)(ws + 60850176);

  cvt_x_kernel<<<16384, 256, 0, stream>>>(features, xb, MROWS * DDIM / 4);
  cvt_cb_cn_kernel<<<KCODES, 256, 0, stream>>>(codebook, cbb, cn);
  transpose_w_kernel<<<2048, 256, 0, stream>>>(w1, w1t, DDIM, HDIM);
  transpose_w_kernel<<<2048, 256, 0, stream>>>(w2, w2t, HDIM, DDIM);

  coarse_kernel<<<(MROWS / 128) * (KCODES / 128), 256, 0, stream>>>(
      xb, cbb, cn, cand2);
  merge_kernel<<<MROWS / 4, 256, 0, stream>>>(cand2, cand);
  rescore_kernel<<<MROWS, 64, 0, stream>>>(features, codebook, cand, idxw, out);

  // decode the codebook (8192 rows), then recon = dec[idx]
  gemm_bt_kernel<1><<<64 * (HDIM / 128), 256, 0, stream>>>(
      cbb, w1t, b1, hb, HDIM, DDIM, HDIM / 128);
  gemm_bt_kernel<2><<<64 * (DDIM / 128), 256, 0, stream>>>(
      hb, w2t, b2, dec, DDIM, HDIM, DDIM / 128);

  epilogue_kernel<<<MROWS, 256, 0, stream>>>(features, codebook, dec, idxw, out);
}

// Round 3
// 743.118 us; speedup vs baseline: 1.4049x; 1.0658x over previous
//
#include <hip/hip_runtime.h>
#include <stdint.h>

// ---------------------------------------------------------------------------
// VQ-VAE quantizer. Coarse bf16-MFMA nearest-code search now uses a 256x256
// tile, 8 waves, BK=32, 3-deep LDS K-tile ring with counted-vmcnt prefetch
// (T3+T4), XOR-swizzled LDS (T2, both-sides: pre-swizzled global source +
// swizzled ds_read), setprio around MFMA clusters (T5).
// Sizes: M=B*T=16384, D=1024, K=8192, H=512.
// ---------------------------------------------------------------------------

#define MROWS  16384
#define DDIM   1024
#define KCODES 8192
#define HDIM   512

typedef __attribute__((ext_vector_type(4))) float  f32x4;
typedef __attribute__((ext_vector_type(8))) __bf16 bf16x8;

__device__ __forceinline__ unsigned short f2bf(float f) {
  uint32_t b = __float_as_uint(f);
  b += 0x7FFFu + ((b >> 16) & 1u);          // RNE
  return (unsigned short)(b >> 16);
}

__device__ __forceinline__ void gload_lds16(const void* g, void* l) {
  __builtin_amdgcn_global_load_lds(
      (__attribute__((address_space(1))) void*)(uintptr_t)g,
      (__attribute__((address_space(3))) void*)(uint32_t)(uintptr_t)l,
      16, 0, 0);
}

__device__ __forceinline__ float waveReduceSum(float v) {
#pragma unroll
  for (int off = 32; off > 0; off >>= 1) v += __shfl_xor(v, off, 64);
  return v;
}

// ---------------------------------------------------------------------------
// K1: features f32 -> bf16
// ---------------------------------------------------------------------------
__global__ __launch_bounds__(256) void cvt_x_kernel(
    const float* __restrict__ in, unsigned short* __restrict__ o, int n4) {
  const int id = blockIdx.x * 256 + threadIdx.x;
  if (id >= n4) return;
  const float4 v = ((const float4*)in)[id];
  ushort4 u;
  u.x = f2bf(v.x); u.y = f2bf(v.y); u.z = f2bf(v.z); u.w = f2bf(v.w);
  ((ushort4*)o)[id] = u;
}

// ---------------------------------------------------------------------------
// K2: codebook f32 -> bf16 + per-row squared norm cn[k]
// ---------------------------------------------------------------------------
__global__ __launch_bounds__(256) void cvt_cb_cn_kernel(
    const float* __restrict__ cb, unsigned short* __restrict__ o,
    float* __restrict__ cn) {
  __shared__ float wsum[4];
  const int k = blockIdx.x, t = threadIdx.x;
  const float4 v = ((const float4*)(cb + (size_t)k * DDIM))[t];
  ushort4 u;
  u.x = f2bf(v.x); u.y = f2bf(v.y); u.z = f2bf(v.z); u.w = f2bf(v.w);
  ((ushort4*)(o + (size_t)k * DDIM))[t] = u;
  float p = v.x * v.x + v.y * v.y + v.z * v.z + v.w * v.w;
  p = waveReduceSum(p);
  if ((t & 63) == 0) wsum[t >> 6] = p;
  __syncthreads();
  if (t == 0) cn[k] = wsum[0] + wsum[1] + wsum[2] + wsum[3];
}

// ---------------------------------------------------------------------------
// K3: weight transpose f32 [R][C] -> bf16 [C][R]
// ---------------------------------------------------------------------------
__global__ __launch_bounds__(256) void transpose_w_kernel(
    const float* __restrict__ w, unsigned short* __restrict__ wt, int R, int C) {
  const int id = blockIdx.x * 256 + threadIdx.x;
  if (id >= R * C) return;
  const int c = id / R, r = id % R;
  wt[id] = f2bf(w[(size_t)r * C + c]);
}

// ---------------------------------------------------------------------------
// K4: coarse scores = cn[k] - 2 * (xb . cbb[k]).
// 256x256 tile, 8 waves (wm 0..1 x wn 0..3), BK=32, NT=32 K-tiles.
// LDS: 3-ring of (A 16KB + B 16KB) = 96KB, subtile-contiguous [256][32] bf16
// rows (64B/row) with XOR swizzle addr = lin ^ (((row>>3)&1)<<5).
// Staging: global_load_lds(16B) with PRE-SWIZZLED global source (inverse map),
// prefetch distance 2 K-tiles, vmcnt(4) + one barrier per K-tile (never 0).
// Epilogue: per-row top-2 over the block's 256 cols -> cand2[row][nb].
// ---------------------------------------------------------------------------
#define COARSE_KT(DO_STAGE)                                                    \
  {                                                                            \
    const int p2 = (p == 0) ? 2 : p - 1; /* (p+2)%3 */                         \
    char* ab = smem + p * 32768;                                               \
    char* sb = smem + p2 * 32768;                                              \
    bf16x8 af[8];                                                              \
    _Pragma("unroll")                                                          \
    for (int mi = 0; mi < 8; ++mi)                                             \
      af[mi] = *reinterpret_cast<const bf16x8*>(ab + aoffs + mi * 1024);       \
    bf16x8 bv0 = *reinterpret_cast<const bf16x8*>(ab + boffs);                 \
    bf16x8 bv1 = *reinterpret_cast<const bf16x8*>(ab + boffs + 1024);          \
    if (DO_STAGE) {                                                            \
      gload_lds16(aP0, sb + dA0);                                              \
      gload_lds16(aP1, sb + dA1);                                              \
    }                                                                          \
    __builtin_amdgcn_s_setprio(1);                                             \
    _Pragma("unroll")                                                          \
    for (int mi = 0; mi < 8; ++mi) {                                           \
      acc[mi][0] = __builtin_amdgcn_mfma_f32_16x16x32_bf16(af[mi], bv0,        \
                                                           acc[mi][0], 0,0,0); \
      acc[mi][1] = __builtin_amdgcn_mfma_f32_16x16x32_bf16(af[mi], bv1,        \
                                                           acc[mi][1], 0,0,0); \
    }                                                                          \
    __builtin_amdgcn_s_setprio(0);                                             \
    bf16x8 bv2 = *reinterpret_cast<const bf16x8*>(ab + boffs + 2048);          \
    bf16x8 bv3 = *reinterpret_cast<const bf16x8*>(ab + boffs + 3072);          \
    if (DO_STAGE) {                                                            \
      gload_lds16(bP0, sb + dB0);                                              \
      gload_lds16(bP1, sb + dB1);                                              \
    }                                                                          \
    __builtin_amdgcn_s_setprio(1);                                             \
    _Pragma("unroll")                                                          \
    for (int mi = 0; mi < 8; ++mi) {                                           \
      acc[mi][2] = __builtin_amdgcn_mfma_f32_16x16x32_bf16(af[mi], bv2,        \
                                                           acc[mi][2], 0,0,0); \
      acc[mi][3] = __builtin_amdgcn_mfma_f32_16x16x32_bf16(af[mi], bv3,        \
                                                           acc[mi][3], 0,0,0); \
    }                                                                          \
    __builtin_amdgcn_s_setprio(0);                                             \
    aP0 += 32; aP1 += 32; bP0 += 32; bP1 += 32;                                \
    p = (p == 2) ? 0 : p + 1;                                                  \
  }

__global__ __launch_bounds__(512, 2) void coarse_kernel(
    const unsigned short* __restrict__ xb,   // [MROWS][DDIM] bf16
    const unsigned short* __restrict__ cbb,  // [KCODES][DDIM] bf16
    const float* __restrict__ cn,            // [KCODES]
    uint32_t* __restrict__ cand2)            // [MROWS][32][4]
{
  __shared__ char  smem[98304];   // 3 x (A 16KB + B 16KB)
  __shared__ uint2 mrg[2048];     // [256 rows][4 wn][2 slots]

  const int tid = threadIdx.x;
  const int l = tid & 63, w = tid >> 6;
  const int lr = l & 15, lg = l >> 4;
  const int wm = w >> 2, wn = w & 3;

  // bijective XCD swizzle (nwg = 2048 = 8 * 256)
  const int bid = blockIdx.x;
  const int swz = (bid & 7) * 256 + (bid >> 3);
  const int mb = swz >> 5, nb = swz & 31;
  const int r0 = mb * 256, c0 = nb * 256;

  // staging decode: LDS slot tid*16 (+j*8192) holds global (srow, scol)
  const int B0 = tid * 16;
  const int lin0 = B0 ^ (((B0 >> 9) & 1) << 5);
  const int srow = lin0 >> 6;          // 0..127
  const int scol = (lin0 & 63) >> 1;   // 0,8,16,24 (elements)

  const unsigned short* aP0 = xb + (size_t)(r0 + srow) * DDIM + scol;
  const unsigned short* aP1 = aP0 + (size_t)128 * DDIM;
  const unsigned short* bP0 = cbb + (size_t)(c0 + srow) * DDIM + scol;
  const unsigned short* bP1 = bP0 + (size_t)128 * DDIM;

  const int dA0 = tid * 16,          dA1 = 8192 + tid * 16;
  const int dB0 = 16384 + tid * 16,  dB1 = 24576 + tid * 16;

  // fragment ds_read offsets (swizzled). XOR bit = (lr>>3)&1 for all mi/ni.
  const int xorb = ((lr >> 3) & 1) << 5;
  const int aoffs = ((wm * 128 + lr) * 64 + lg * 16) ^ xorb;
  const int boffs = 16384 + (((wn * 64 + lr) * 64 + lg * 16) ^ xorb);

  f32x4 acc[8][4];
#pragma unroll
  for (int mi = 0; mi < 8; ++mi)
#pragma unroll
    for (int ni = 0; ni < 4; ++ni) acc[mi][ni] = 0.0f;

  // prologue: stage kt0 -> buf0, kt1 -> buf1 (8 loads in flight)
  gload_lds16(aP0, smem + dA0);
  gload_lds16(aP1, smem + dA1);
  gload_lds16(bP0, smem + dB0);
  gload_lds16(bP1, smem + dB1);
  gload_lds16(aP0 + 32, smem + 32768 + dA0);
  gload_lds16(aP1 + 32, smem + 32768 + dA1);
  gload_lds16(bP0 + 32, smem + 32768 + dB0);
  gload_lds16(bP1 + 32, smem + 32768 + dB1);
  aP0 += 64; aP1 += 64; bP0 += 64; bP1 += 64;   // next stage target: kt+2

  int p = 0;
#pragma unroll 1
  for (int kt = 0; kt < 31; ++kt) {
    __builtin_amdgcn_sched_barrier(0);
    asm volatile("s_waitcnt vmcnt(4)" ::: "memory");  // kt's loads landed
    __builtin_amdgcn_s_barrier();
    __builtin_amdgcn_sched_barrier(0);
    const bool ds = (kt < 30);                        // stage kt+2 while kt+2<NT
    COARSE_KT(ds)
  }
  // last K-tile: its loads are the only possibly-outstanding ones
  __builtin_amdgcn_sched_barrier(0);
  asm volatile("s_waitcnt vmcnt(0)" ::: "memory");
  __builtin_amdgcn_s_barrier();
  __builtin_amdgcn_sched_barrier(0);
  COARSE_KT(false)

  // ------------------ fold: per-row top-2 over this block's 256 cols ------
  float cnv[4];
#pragma unroll
  for (int ni = 0; ni < 4; ++ni) cnv[ni] = cn[c0 + wn * 64 + ni * 16 + lr];

#pragma unroll
  for (int mi = 0; mi < 8; ++mi) {
#pragma unroll
    for (int r = 0; r < 4; ++r) {
      float s1 = __builtin_inff(), s2 = __builtin_inff();
      int   i1 = KCODES, i2 = KCODES;
#pragma unroll
      for (int ni = 0; ni < 4; ++ni) {
        const float s = fmaf(-2.0f, acc[mi][ni][r], cnv[ni]);
        const int col = c0 + wn * 64 + ni * 16 + lr;
        const bool lt1 = s < s1;
        const bool lt2 = s < s2;
        s2 = lt1 ? s1 : (lt2 ? s   : s2);
        i2 = lt1 ? i1 : (lt2 ? col : i2);
        s1 = lt1 ? s   : s1;
        i1 = lt1 ? col : i1;
      }
      // butterfly over the 16 lanes sharing this row
#pragma unroll
      for (int off = 1; off < 16; off <<= 1) {
        const float t1 = __shfl_xor(s1, off, 64);
        const int   j1 = __shfl_xor(i1, off, 64);
        const float t2 = __shfl_xor(s2, off, 64);
        const int   j2 = __shfl_xor(i2, off, 64);
        const bool c1 = (t1 < s1) || (t1 == s1 && j1 < i1);
        const float w1s = c1 ? t1 : s1; const int w1i = c1 ? j1 : i1;
        const float l1s = c1 ? s1 : t1; const int l1i = c1 ? i1 : j1;
        const bool c2 = (t2 < s2) || (t2 == s2 && j2 < i2);
        const float m2s = c2 ? t2 : s2; const int m2i = c2 ? j2 : i2;
        const bool c3 = (m2s < l1s) || (m2s == l1s && m2i < l1i);
        s2 = c3 ? m2s : l1s; i2 = c3 ? m2i : l1i;
        s1 = w1s;            i1 = w1i;
      }
      if (lr == 0) {
        const int r256 = wm * 128 + mi * 16 + lg * 4 + r;
        uint2 e0; e0.x = __float_as_uint(s1); e0.y = (uint32_t)i1;
        uint2 e1; e1.x = __float_as_uint(s2); e1.y = (uint32_t)i2;
        mrg[(r256 * 4 + wn) * 2 + 0] = e0;
        mrg[(r256 * 4 + wn) * 2 + 1] = e1;
      }
    }
  }
  __syncthreads();

  if (tid < 256) {
    float s1 = __builtin_inff(), s2 = __builtin_inff();
    int   i1 = KCODES, i2 = KCODES;
    const uint2* mp = mrg + tid * 8;
#pragma unroll
    for (int t = 0; t < 8; ++t) {
      const float s = __uint_as_float(mp[t].x);
      const int   i = (int)mp[t].y;
      if (s < s1 || (s == s1 && i < i1)) { s2 = s1; i2 = i1; s1 = s; i1 = i; }
      else if (s < s2 || (s == s2 && i < i2)) { s2 = s; i2 = i; }
    }
    uint4 o;
    o.x = __float_as_uint(s1); o.y = (uint32_t)i1;
    o.z = __float_as_uint(s2); o.w = (uint32_t)i2;
    *((uint4*)(cand2 + ((size_t)(r0 + tid) * 32 + nb) * 4)) = o;
  }
}

// ---------------------------------------------------------------------------
// K4b: per-row top-8 of 64 (score,idx) candidates (32 blocks x 2).
// 4 rows per 256-thread block; lane l holds pair l.
// ---------------------------------------------------------------------------
__global__ __launch_bounds__(256) void merge_kernel(
    const uint32_t* __restrict__ cand2, uint32_t* __restrict__ cand) {
  const int row = blockIdx.x * 4 + (threadIdx.x >> 6);
  const int l = threadIdx.x & 63;
  const uint2 v = ((const uint2*)(cand2 + (size_t)row * 128))[l];
  float s = __uint_as_float(v.x); int i = (int)v.y;
  uint32_t* cp = cand + (size_t)row * 16;
#pragma unroll
  for (int t = 0; t < 8; ++t) {
    float bm = s; int bi = i;
#pragma unroll
    for (int off = 1; off < 64; off <<= 1) {
      const float os = __shfl_xor(bm, off, 64);
      const int   oi = __shfl_xor(bi, off, 64);
      if (os < bm || (os == bm && oi < bi)) { bm = os; bi = oi; }
    }
    if (l == 0) { cp[t * 2] = __float_as_uint(bm); cp[t * 2 + 1] = (uint32_t)bi; }
    if (i == bi) { s = __builtin_inff(); i = 0x7FFFFFFF; }
  }
}

// ---------------------------------------------------------------------------
// K5: exact fp32 rescore of candidates within coarse margin; fast path when
// only one candidate is within min+2.5.
// ---------------------------------------------------------------------------
__global__ __launch_bounds__(64) void rescore_kernel(
    const float* __restrict__ x, const float* __restrict__ cb,
    const uint32_t* __restrict__ cand, int* __restrict__ idx_ws,
    float* __restrict__ out) {
  const int r = blockIdx.x;
  const int l = threadIdx.x;
  if (r == 0 && l == 0) out[(size_t)MROWS * DDIM + MROWS] = 0.0f;

  float cs[8]; int ci[8];
#pragma unroll
  for (int c = 0; c < 8; ++c) {
    cs[c] = __uint_as_float(cand[((size_t)r * 8 + c) * 2]);
    ci[c] = (int)cand[((size_t)r * 8 + c) * 2 + 1];
  }
  float smin = cs[0]; int simin = ci[0];
#pragma unroll
  for (int c = 1; c < 8; ++c)
    if (cs[c] < smin || (cs[c] == smin && ci[c] < simin)) { smin = cs[c]; simin = ci[c]; }
  const float thresh = smin + 2.5f;
  int cnt = 0;
#pragma unroll
  for (int c = 0; c < 8; ++c) cnt += (cs[c] <= thresh) ? 1 : 0;

  if (cnt == 1) {
    if (l == 0) {
      idx_ws[r] = simin;
      out[(size_t)MROWS * DDIM + r] = (float)simin;
    }
    return;
  }

  const float4* x4 = (const float4*)(x + (size_t)r * DDIM);
  float4 xv[4];
#pragma unroll
  for (int i = 0; i < 4; ++i) xv[i] = x4[i * 64 + l];

  float bestS = __builtin_inff(); int bestI = KCODES;
  for (int c = 0; c < 8; ++c) {
    if (cs[c] > thresh) continue;               // wave-uniform branch
    const int code = ci[c];
    const float4* c4 = (const float4*)(cb + (size_t)code * DDIM);
    float dot = 0.f, nn = 0.f;
#pragma unroll
    for (int i = 0; i < 4; ++i) {
      const float4 cv = c4[i * 64 + l];
      dot = fmaf(xv[i].x, cv.x, dot); dot = fmaf(xv[i].y, cv.y, dot);
      dot = fmaf(xv[i].z, cv.z, dot); dot = fmaf(xv[i].w, cv.w, dot);
      nn  = fmaf(cv.x, cv.x, nn);     nn  = fmaf(cv.y, cv.y, nn);
      nn  = fmaf(cv.z, cv.z, nn);     nn  = fmaf(cv.w, cv.w, nn);
    }
#pragma unroll
    for (int off = 32; off > 0; off >>= 1) {
      dot += __shfl_xor(dot, off, 64);
      nn  += __shfl_xor(nn,  off, 64);
    }
    const float sc = nn - 2.0f * dot;
    if (sc < bestS || (sc == bestS && code < bestI)) { bestS = sc; bestI = code; }
  }
  if (l == 0) {
    idx_ws[r] = bestI;
    out[(size_t)MROWS * DDIM + r] = (float)bestI;
  }
}

// ---------------------------------------------------------------------------
// K6/K7: bf16 GEMM C = A[M][K] * B[N][K]^T (+bias). EPI==1: relu->bf16.
// EPI==2: f32 store.
// ---------------------------------------------------------------------------
template <int EPI>
__global__ __launch_bounds__(256) void gemm_bt_kernel(
    const unsigned short* __restrict__ A, const unsigned short* __restrict__ B,
    const float* __restrict__ bias, void* __restrict__ outp,
    int Nsize, int Kred, int nblk) {
  __shared__ unsigned short As[128 * 32];
  __shared__ unsigned short Bs[128 * 32];
  const int tid = threadIdx.x;
  const int l = tid & 63, w = tid >> 6;
  const int lr = l & 15, lg = l >> 4;
  const int wm = w >> 1, wn = w & 1;
  const int mb = blockIdx.x / nblk, nb = blockIdx.x % nblk;
  const int r0 = mb * 128, c0 = nb * 128;
  const int prow = tid >> 2, pcol = (tid & 3) * 8;

  f32x4 acc[4][4];
#pragma unroll
  for (int mi = 0; mi < 4; ++mi)
#pragma unroll
    for (int ni = 0; ni < 4; ++ni) acc[mi][ni] = 0.0f;

  const size_t aoff0 = (size_t)(r0 + prow) * Kred + pcol;
  const size_t aoff1 = aoff0 + (size_t)64 * Kred;
  const size_t boff0 = (size_t)(c0 + prow) * Kred + pcol;
  const size_t boff1 = boff0 + (size_t)64 * Kred;

  const int nks = Kred >> 5;
  for (int ks = 0; ks < nks; ++ks) {
    const int k0 = ks * 32;
    gload_lds16(A + aoff0 + k0, &As[tid * 8]);
    gload_lds16(A + aoff1 + k0, &As[2048 + tid * 8]);
    gload_lds16(B + boff0 + k0, &Bs[tid * 8]);
    gload_lds16(B + boff1 + k0, &Bs[2048 + tid * 8]);
    __syncthreads();

    bf16x8 af[4], bfv[4];
#pragma unroll
    for (int mi = 0; mi < 4; ++mi)
      af[mi] = *reinterpret_cast<const bf16x8*>(
          &As[(wm * 64 + mi * 16 + lr) * 32 + lg * 8]);
#pragma unroll
    for (int ni = 0; ni < 4; ++ni)
      bfv[ni] = *reinterpret_cast<const bf16x8*>(
          &Bs[(wn * 64 + ni * 16 + lr) * 32 + lg * 8]);
#pragma unroll
    for (int mi = 0; mi < 4; ++mi)
#pragma unroll
      for (int ni = 0; ni < 4; ++ni)
        acc[mi][ni] = __builtin_amdgcn_mfma_f32_16x16x32_bf16(
            af[mi], bfv[ni], acc[mi][ni], 0, 0, 0);
    __syncthreads();
  }

#pragma unroll
  for (int ni = 0; ni < 4; ++ni) {
    const int col = c0 + wn * 64 + ni * 16 + lr;
    const float bv = bias[col];
#pragma unroll
    for (int mi = 0; mi < 4; ++mi) {
#pragma unroll
      for (int r = 0; r < 4; ++r) {
        const int row = r0 + wm * 64 + mi * 16 + lg * 4 + r;
        const float v = acc[mi][ni][r] + bv;
        if (EPI == 1) {
          ((unsigned short*)outp)[(size_t)row * Nsize + col] =
              f2bf(fmaxf(v, 0.0f));
        } else {
          ((float*)outp)[(size_t)row * Nsize + col] = v;
        }
      }
    }
  }
}

// ---------------------------------------------------------------------------
// K8: recon[row] = dec[idx[row]] gather-write + fused commitment loss.
// ---------------------------------------------------------------------------
__global__ __launch_bounds__(256) void epilogue_kernel(
    const float* __restrict__ x, const float* __restrict__ cb,
    const float* __restrict__ dec, const int* __restrict__ idx_ws,
    float* __restrict__ out) {
  __shared__ float wsum[4];
  const int r = blockIdx.x, t = threadIdx.x;
  const int code = idx_ws[r];
  const float4 dv = ((const float4*)(dec + (size_t)code * DDIM))[t];
  ((float4*)(out + (size_t)r * DDIM))[t] = dv;
  const float4 xv = ((const float4*)(x + (size_t)r * DDIM))[t];
  const float4 cv = ((const float4*)(cb + (size_t)code * DDIM))[t];
  const float ex = xv.x - cv.x, ey = xv.y - cv.y;
  const float ez = xv.z - cv.z, ew = xv.w - cv.w;
  float pr = ex * ex + ey * ey + ez * ez + ew * ew;
  pr = waveReduceSum(pr);
  if ((t & 63) == 0) wsum[t >> 6] = pr;
  __syncthreads();
  if (t == 0) {
    const float total = wsum[0] + wsum[1] + wsum[2] + wsum[3];
    atomicAdd(out + (size_t)MROWS * DDIM + MROWS, total * (0.25f / 16777216.0f));
  }
}

// ---------------------------------------------------------------------------
extern "C" void kernel_launch(void* const* d_in, const int* in_sizes, int n_in,
                              void* d_out, int out_size, void* d_ws,
                              size_t ws_size, hipStream_t stream) {
  const float* features = (const float*)d_in[0];  // [8,2048,1024]
  const float* codebook = (const float*)d_in[1];  // [8192,1024]
  const float* w1 = (const float*)d_in[2];        // [1024,512]
  const float* b1 = (const float*)d_in[3];        // [512]
  const float* w2 = (const float*)d_in[4];        // [512,1024]
  const float* b2 = (const float*)d_in[5];        // [1024]
  float* out = (float*)d_out;
  char* ws = (char*)d_ws;

  unsigned short* xb  = (unsigned short*)(ws + 0);         // 33,554,432
  unsigned short* cbb = (unsigned short*)(ws + 33554432);  // 16,777,216
  float*          cn  = (float*)(ws + 50331648);           //     32,768
  unsigned short* w1t = (unsigned short*)(ws + 50364416);  //  1,048,576
  unsigned short* w2t = (unsigned short*)(ws + 51412992);  //  1,048,576
  unsigned short* hb  = (unsigned short*)(ws + 52461568);  //  8,388,608
  float*          dec = (float*)(ws + 60850176);           // 33,554,432
  uint32_t*       cand = (uint32_t*)(ws + 94404608);       //  1,048,576
  int*            idxw = (int*)(ws + 95453184);            //     65,536
  // cand2 (8 MB) aliases dec: consumed by merge_kernel BEFORE gemm<2>
  // writes dec (stream-ordered -> safe).
  uint32_t*       cand2 = (uint32_t*)(ws + 60850176);

  cvt_x_kernel<<<16384, 256, 0, stream>>>(features, xb, MROWS * DDIM / 4);
  cvt_cb_cn_kernel<<<KCODES, 256, 0, stream>>>(codebook, cbb, cn);
  transpose_w_kernel<<<2048, 256, 0, stream>>>(w1, w1t, DDIM, HDIM);
  transpose_w_kernel<<<2048, 256, 0, stream>>>(w2, w2t, HDIM, DDIM);

  coarse_kernel<<<(MROWS / 256) * (KCODES / 256), 512, 0, stream>>>(
      xb, cbb, cn, cand2);
  merge_kernel<<<MROWS / 4, 256, 0, stream>>>(cand2, cand);
  rescore_kernel<<<MROWS, 64, 0, stream>>>(features, codebook, cand, idxw, out);

  // decode the codebook (8192 rows), then recon = dec[idx]
  gemm_bt_kernel<1><<<64 * (HDIM / 128), 256, 0, stream>>>(
      cbb, w1t, b1, hb, HDIM, DDIM, HDIM / 128);
  gemm_bt_kernel<2><<<64 * (DDIM / 128), 256, 0, stream>>>(
      hb, w2t, b2, dec, DDIM, HDIM, DDIM / 128);

  epilogue_kernel<<<MROWS, 256, 0, stream>>>(features, codebook, dec, idxw, out);
}

// Round 4
// 706.188 us; speedup vs baseline: 1.4784x; 1.0523x over previous
//
#include <hip/hip_runtime.h>
#include <stdint.h>

// ---------------------------------------------------------------------------
// VQ-VAE quantizer. Coarse search: 256x128 tile, 4 waves (2x2), BK=32,
// ring-3 LDS (72KB -> 2 blocks/CU for cross-block MFMA/LDS overlap),
// counted vmcnt(6) prefetch (T4), 2-way-free XOR swizzle (T2), setprio (T5).
// Sizes: M=B*T=16384, D=1024, K=8192 codes, H=512.
// ---------------------------------------------------------------------------

#define MROWS  16384
#define DDIM   1024
#define KCODES 8192
#define HDIM   512
#define RING   24576   // per ring slot: A 16KB + B 8KB

typedef __attribute__((ext_vector_type(4))) float  f32x4;
typedef __attribute__((ext_vector_type(8))) __bf16 bf16x8;

__device__ __forceinline__ unsigned short f2bf(float f) {
  uint32_t b = __float_as_uint(f);
  b += 0x7FFFu + ((b >> 16) & 1u);          // RNE
  return (unsigned short)(b >> 16);
}

__device__ __forceinline__ void gload_lds16(const void* g, void* l) {
  __builtin_amdgcn_global_load_lds(
      (__attribute__((address_space(1))) void*)(uintptr_t)g,
      (__attribute__((address_space(3))) void*)(uint32_t)(uintptr_t)l,
      16, 0, 0);
}

__device__ __forceinline__ float waveReduceSum(float v) {
#pragma unroll
  for (int off = 32; off > 0; off >>= 1) v += __shfl_xor(v, off, 64);
  return v;
}

// ---------------------------------------------------------------------------
// K1: features f32 -> bf16
// ---------------------------------------------------------------------------
__global__ __launch_bounds__(256) void cvt_x_kernel(
    const float* __restrict__ in, unsigned short* __restrict__ o, int n4) {
  const int id = blockIdx.x * 256 + threadIdx.x;
  if (id >= n4) return;
  const float4 v = ((const float4*)in)[id];
  ushort4 u;
  u.x = f2bf(v.x); u.y = f2bf(v.y); u.z = f2bf(v.z); u.w = f2bf(v.w);
  ((ushort4*)o)[id] = u;
}

// ---------------------------------------------------------------------------
// K2: codebook f32 -> bf16 + per-row squared norm cn[k]
// ---------------------------------------------------------------------------
__global__ __launch_bounds__(256) void cvt_cb_cn_kernel(
    const float* __restrict__ cb, unsigned short* __restrict__ o,
    float* __restrict__ cn) {
  __shared__ float wsum[4];
  const int k = blockIdx.x, t = threadIdx.x;
  const float4 v = ((const float4*)(cb + (size_t)k * DDIM))[t];
  ushort4 u;
  u.x = f2bf(v.x); u.y = f2bf(v.y); u.z = f2bf(v.z); u.w = f2bf(v.w);
  ((ushort4*)(o + (size_t)k * DDIM))[t] = u;
  float p = v.x * v.x + v.y * v.y + v.z * v.z + v.w * v.w;
  p = waveReduceSum(p);
  if ((t & 63) == 0) wsum[t >> 6] = p;
  __syncthreads();
  if (t == 0) cn[k] = wsum[0] + wsum[1] + wsum[2] + wsum[3];
}

// ---------------------------------------------------------------------------
// K3: weight transpose f32 [R][C] -> bf16 [C][R]
// ---------------------------------------------------------------------------
__global__ __launch_bounds__(256) void transpose_w_kernel(
    const float* __restrict__ w, unsigned short* __restrict__ wt, int R, int C) {
  const int id = blockIdx.x * 256 + threadIdx.x;
  if (id >= R * C) return;
  const int c = id / R, r = id % R;
  wt[id] = f2bf(w[(size_t)r * C + c]);
}

// ---------------------------------------------------------------------------
// K4: coarse scores = cn[k] - 2 * (xb . cbb[k]).
// 256 rows x 128 codes per block, 4 waves (wm 0..1 x wn 0..1), BK=32,
// 32 K-tiles. Ring-3 LDS slots of (A[256][32] + B[128][32]) bf16, rows 64B,
// XOR swizzle byte ^= ((row>>1)&3)<<4 (2-way conflicts = free), staged via
// pre-swizzled global source. Prefetch distance 2 KT, vmcnt(6) per KT.
// Fold: per-row top-2 over 128 cols -> cand2[row][nb] (nb 0..63).
// ---------------------------------------------------------------------------
#define COARSE_KT(DO_STAGE)                                                    \
  {                                                                            \
    const int p2 = (p == 0) ? 2 : p - 1; /* (p+2)%3 */                         \
    char* ab = smem + p * RING;                                                \
    char* sb_ = smem + p2 * RING;                                              \
    bf16x8 af[8];                                                              \
    _Pragma("unroll")                                                          \
    for (int mi = 0; mi < 8; ++mi)                                             \
      af[mi] = *reinterpret_cast<const bf16x8*>(ab + aoffs + mi * 1024);       \
    bf16x8 bv0 = *reinterpret_cast<const bf16x8*>(ab + boffs);                 \
    bf16x8 bv1 = *reinterpret_cast<const bf16x8*>(ab + boffs + 1024);          \
    if (DO_STAGE) {                                                            \
      gload_lds16(aS0, sb_ + (dA + 0));                                        \
      gload_lds16(aS1, sb_ + (dA + 4096));                                     \
      gload_lds16(aS2, sb_ + (dA + 8192));                                     \
    }                                                                          \
    __builtin_amdgcn_s_setprio(1);                                             \
    _Pragma("unroll")                                                          \
    for (int mi = 0; mi < 8; ++mi) {                                           \
      acc[mi][0] = __builtin_amdgcn_mfma_f32_16x16x32_bf16(af[mi], bv0,        \
                                                           acc[mi][0], 0,0,0); \
      acc[mi][1] = __builtin_amdgcn_mfma_f32_16x16x32_bf16(af[mi], bv1,        \
                                                           acc[mi][1], 0,0,0); \
    }                                                                          \
    __builtin_amdgcn_s_setprio(0);                                             \
    bf16x8 bv2 = *reinterpret_cast<const bf16x8*>(ab + boffs + 2048);          \
    bf16x8 bv3 = *reinterpret_cast<const bf16x8*>(ab + boffs + 3072);          \
    if (DO_STAGE) {                                                            \
      gload_lds16(aS3, sb_ + (dA + 12288));                                    \
      gload_lds16(bS0, sb_ + (dB + 0));                                        \
      gload_lds16(bS1, sb_ + (dB + 4096));                                     \
    }                                                                          \
    __builtin_amdgcn_s_setprio(1);                                             \
    _Pragma("unroll")                                                          \
    for (int mi = 0; mi < 8; ++mi) {                                           \
      acc[mi][2] = __builtin_amdgcn_mfma_f32_16x16x32_bf16(af[mi], bv2,        \
                                                           acc[mi][2], 0,0,0); \
      acc[mi][3] = __builtin_amdgcn_mfma_f32_16x16x32_bf16(af[mi], bv3,        \
                                                           acc[mi][3], 0,0,0); \
    }                                                                          \
    __builtin_amdgcn_s_setprio(0);                                             \
    aS0 += 32; aS1 += 32; aS2 += 32; aS3 += 32; bS0 += 32; bS1 += 32;          \
    p = (p == 2) ? 0 : p + 1;                                                  \
  }

__global__ __launch_bounds__(256, 2) void coarse_kernel(
    const unsigned short* __restrict__ xb,   // [MROWS][DDIM] bf16
    const unsigned short* __restrict__ cbb,  // [KCODES][DDIM] bf16
    const float* __restrict__ cn,            // [KCODES]
    uint32_t* __restrict__ cand2)            // [MROWS][64][4]
{
  __shared__ char smem[73728];   // 3 x (A 16KB + B 8KB); fold scratch aliased

  const int tid = threadIdx.x;
  const int l = tid & 63, w = tid >> 6;
  const int lr = l & 15, lg = l >> 4;
  const int wm = w >> 1, wn = w & 1;

  // bijective XCD swizzle (nwg = 4096 = 8 * 512)
  const int bid = blockIdx.x;
  const int swz = (bid & 7) * 512 + (bid >> 3);
  const int mb = swz >> 6, nb = swz & 63;
  const int r0 = mb * 256, c0 = nb * 128;

  // staging: dest D (linear tid*16 within round) holds global
  // (row = D>>6, col = ((D&63) ^ (((row>>1)&3)<<4))>>1)
  const int srow = tid >> 2;                                   // 0..63
  const int scol = (((tid & 3) * 16) ^ (((tid >> 3) & 3) << 4)) >> 1;

  const unsigned short* aS0 = xb + (size_t)(r0 + srow) * DDIM + scol;
  const unsigned short* aS1 = aS0 + (size_t)64 * DDIM;
  const unsigned short* aS2 = aS0 + (size_t)128 * DDIM;
  const unsigned short* aS3 = aS0 + (size_t)192 * DDIM;
  const unsigned short* bS0 = cbb + (size_t)(c0 + srow) * DDIM + scol;
  const unsigned short* bS1 = bS0 + (size_t)64 * DDIM;

  const int dA = tid * 16;            // + round*4096, rounds 0..3
  const int dB = 16384 + tid * 16;    // + round*4096, rounds 0..1

  // fragment ds_read byte offsets (swizzled; xor bits only in bits 4-5)
  const int xorb = ((lr >> 1) & 3) << 4;
  const int aoffs = (wm * 128 + lr) * 64 + ((lg * 16) ^ xorb);
  const int boffs = 16384 + (wn * 64 + lr) * 64 + ((lg * 16) ^ xorb);

  f32x4 acc[8][4];
#pragma unroll
  for (int mi = 0; mi < 8; ++mi)
#pragma unroll
    for (int ni = 0; ni < 4; ++ni) acc[mi][ni] = 0.0f;

  // prologue: stage kt0 -> slot0, kt1 -> slot1 (12 loads in flight)
  gload_lds16(aS0, smem + dA + 0);
  gload_lds16(aS1, smem + dA + 4096);
  gload_lds16(aS2, smem + dA + 8192);
  gload_lds16(aS3, smem + dA + 12288);
  gload_lds16(bS0, smem + dB + 0);
  gload_lds16(bS1, smem + dB + 4096);
  gload_lds16(aS0 + 32, smem + RING + dA + 0);
  gload_lds16(aS1 + 32, smem + RING + dA + 4096);
  gload_lds16(aS2 + 32, smem + RING + dA + 8192);
  gload_lds16(aS3 + 32, smem + RING + dA + 12288);
  gload_lds16(bS0 + 32, smem + RING + dB + 0);
  gload_lds16(bS1 + 32, smem + RING + dB + 4096);
  aS0 += 64; aS1 += 64; aS2 += 64; aS3 += 64; bS0 += 64; bS1 += 64;

  int p = 0;
#pragma unroll 1
  for (int kt = 0; kt < 31; ++kt) {
    __builtin_amdgcn_sched_barrier(0);
    asm volatile("s_waitcnt vmcnt(6)" ::: "memory");  // kt's 6 loads landed
    __builtin_amdgcn_s_barrier();
    __builtin_amdgcn_sched_barrier(0);
    const bool ds = (kt < 30);                        // stage kt+2 while valid
    COARSE_KT(ds)
  }
  __builtin_amdgcn_sched_barrier(0);
  asm volatile("s_waitcnt vmcnt(0)" ::: "memory");
  __builtin_amdgcn_s_barrier();
  __builtin_amdgcn_sched_barrier(0);
  COARSE_KT(false)

  __syncthreads();   // ring dead; smem reused as fold scratch
  uint2* mrg = (uint2*)smem;   // [256 rows][2 wn][2 slots]

  float cnv[4];
#pragma unroll
  for (int ni = 0; ni < 4; ++ni) cnv[ni] = cn[c0 + wn * 64 + ni * 16 + lr];

#pragma unroll
  for (int mi = 0; mi < 8; ++mi) {
#pragma unroll
    for (int r = 0; r < 4; ++r) {
      float s1 = __builtin_inff(), s2 = __builtin_inff();
      int   i1 = KCODES, i2 = KCODES;
#pragma unroll
      for (int ni = 0; ni < 4; ++ni) {
        const float s = fmaf(-2.0f, acc[mi][ni][r], cnv[ni]);
        const int col = c0 + wn * 64 + ni * 16 + lr;
        const bool lt1 = s < s1;
        const bool lt2 = s < s2;
        s2 = lt1 ? s1 : (lt2 ? s   : s2);
        i2 = lt1 ? i1 : (lt2 ? col : i2);
        s1 = lt1 ? s   : s1;
        i1 = lt1 ? col : i1;
      }
      // butterfly over the 16 lanes sharing this row
#pragma unroll
      for (int off = 1; off < 16; off <<= 1) {
        const float t1 = __shfl_xor(s1, off, 64);
        const int   j1 = __shfl_xor(i1, off, 64);
        const float t2 = __shfl_xor(s2, off, 64);
        const int   j2 = __shfl_xor(i2, off, 64);
        const bool c1 = (t1 < s1) || (t1 == s1 && j1 < i1);
        const float w1s = c1 ? t1 : s1; const int w1i = c1 ? j1 : i1;
        const float l1s = c1 ? s1 : t1; const int l1i = c1 ? i1 : j1;
        const bool c2 = (t2 < s2) || (t2 == s2 && j2 < i2);
        const float m2s = c2 ? t2 : s2; const int m2i = c2 ? j2 : i2;
        const bool c3 = (m2s < l1s) || (m2s == l1s && m2i < l1i);
        s2 = c3 ? m2s : l1s; i2 = c3 ? m2i : l1i;
        s1 = w1s;            i1 = w1i;
      }
      if (lr == 0) {
        const int row = wm * 128 + mi * 16 + lg * 4 + r;
        uint2 e0; e0.x = __float_as_uint(s1); e0.y = (uint32_t)i1;
        uint2 e1; e1.x = __float_as_uint(s2); e1.y = (uint32_t)i2;
        mrg[(row * 2 + wn) * 2 + 0] = e0;
        mrg[(row * 2 + wn) * 2 + 1] = e1;
      }
    }
  }
  __syncthreads();

  {
    const int row = tid;   // 0..255
    float s1 = __builtin_inff(), s2 = __builtin_inff();
    int   i1 = KCODES, i2 = KCODES;
    const uint2* mp = mrg + row * 4;
#pragma unroll
    for (int t = 0; t < 4; ++t) {
      const float s = __uint_as_float(mp[t].x);
      const int   i = (int)mp[t].y;
      if (s < s1 || (s == s1 && i < i1)) { s2 = s1; i2 = i1; s1 = s; i1 = i; }
      else if (s < s2 || (s == s2 && i < i2)) { s2 = s; i2 = i; }
    }
    uint4 o;
    o.x = __float_as_uint(s1); o.y = (uint32_t)i1;
    o.z = __float_as_uint(s2); o.w = (uint32_t)i2;
    *((uint4*)(cand2 + ((size_t)(r0 + row) * 64 + nb) * 4)) = o;
  }
}

// ---------------------------------------------------------------------------
// K4b: per-row top-8 of the 128 (score,idx) candidates (64 blocks x 2).
// 4 rows per block (1 wave each); lane l holds colblk l's 2 pairs.
// ---------------------------------------------------------------------------
__global__ __launch_bounds__(256) void merge_kernel(
    const uint32_t* __restrict__ cand2, uint32_t* __restrict__ cand) {
  const int row = blockIdx.x * 4 + (threadIdx.x >> 6);
  const int l = threadIdx.x & 63;
  const uint4 v = ((const uint4*)(cand2 + (size_t)row * 256))[l];
  float sA = __uint_as_float(v.x); int iA = (int)v.y;
  float sB = __uint_as_float(v.z); int iB = (int)v.w;
  uint32_t* cp = cand + (size_t)row * 16;
#pragma unroll
  for (int t = 0; t < 8; ++t) {
    float bm; int bi;
    if (sA < sB || (sA == sB && iA < iB)) { bm = sA; bi = iA; }
    else                                  { bm = sB; bi = iB; }
#pragma unroll
    for (int off = 1; off < 64; off <<= 1) {
      const float os = __shfl_xor(bm, off, 64);
      const int   oi = __shfl_xor(bi, off, 64);
      if (os < bm || (os == bm && oi < bi)) { bm = os; bi = oi; }
    }
    if (l == 0) { cp[t * 2] = __float_as_uint(bm); cp[t * 2 + 1] = (uint32_t)bi; }
    if (iA == bi) { sA = __builtin_inff(); iA = 0x7FFFFFFF; }
    if (iB == bi) { sB = __builtin_inff(); iB = 0x7FFFFFFF; }
  }
}

// ---------------------------------------------------------------------------
// K5: exact fp32 rescore of candidates within coarse margin; fast path when
// only one candidate is within min+2.5.
// ---------------------------------------------------------------------------
__global__ __launch_bounds__(64) void rescore_kernel(
    const float* __restrict__ x, const float* __restrict__ cb,
    const uint32_t* __restrict__ cand, int* __restrict__ idx_ws,
    float* __restrict__ out) {
  const int r = blockIdx.x;
  const int l = threadIdx.x;
  if (r == 0 && l == 0) out[(size_t)MROWS * DDIM + MROWS] = 0.0f;

  float cs[8]; int ci[8];
#pragma unroll
  for (int c = 0; c < 8; ++c) {
    cs[c] = __uint_as_float(cand[((size_t)r * 8 + c) * 2]);
    ci[c] = (int)cand[((size_t)r * 8 + c) * 2 + 1];
  }
  float smin = cs[0]; int simin = ci[0];
#pragma unroll
  for (int c = 1; c < 8; ++c)
    if (cs[c] < smin || (cs[c] == smin && ci[c] < simin)) { smin = cs[c]; simin = ci[c]; }
  const float thresh = smin + 2.5f;
  int cnt = 0;
#pragma unroll
  for (int c = 0; c < 8; ++c) cnt += (cs[c] <= thresh) ? 1 : 0;

  if (cnt == 1) {
    if (l == 0) {
      idx_ws[r] = simin;
      out[(size_t)MROWS * DDIM + r] = (float)simin;
    }
    return;
  }

  const float4* x4 = (const float4*)(x + (size_t)r * DDIM);
  float4 xv[4];
#pragma unroll
  for (int i = 0; i < 4; ++i) xv[i] = x4[i * 64 + l];

  float bestS = __builtin_inff(); int bestI = KCODES;
  for (int c = 0; c < 8; ++c) {
    if (cs[c] > thresh) continue;               // wave-uniform branch
    const int code = ci[c];
    const float4* c4 = (const float4*)(cb + (size_t)code * DDIM);
    float dot = 0.f, nn = 0.f;
#pragma unroll
    for (int i = 0; i < 4; ++i) {
      const float4 cv = c4[i * 64 + l];
      dot = fmaf(xv[i].x, cv.x, dot); dot = fmaf(xv[i].y, cv.y, dot);
      dot = fmaf(xv[i].z, cv.z, dot); dot = fmaf(xv[i].w, cv.w, dot);
      nn  = fmaf(cv.x, cv.x, nn);     nn  = fmaf(cv.y, cv.y, nn);
      nn  = fmaf(cv.z, cv.z, nn);     nn  = fmaf(cv.w, cv.w, nn);
    }
#pragma unroll
    for (int off = 32; off > 0; off >>= 1) {
      dot += __shfl_xor(dot, off, 64);
      nn  += __shfl_xor(nn,  off, 64);
    }
    const float sc = nn - 2.0f * dot;
    if (sc < bestS || (sc == bestS && code < bestI)) { bestS = sc; bestI = code; }
  }
  if (l == 0) {
    idx_ws[r] = bestI;
    out[(size_t)MROWS * DDIM + r] = (float)bestI;
  }
}

// ---------------------------------------------------------------------------
// K6/K7: bf16 GEMM C = A[M][K] * B[N][K]^T (+bias). EPI==1: relu->bf16.
// EPI==2: f32 store.
// ---------------------------------------------------------------------------
template <int EPI>
__global__ __launch_bounds__(256) void gemm_bt_kernel(
    const unsigned short* __restrict__ A, const unsigned short* __restrict__ B,
    const float* __restrict__ bias, void* __restrict__ outp,
    int Nsize, int Kred, int nblk) {
  __shared__ unsigned short As[128 * 32];
  __shared__ unsigned short Bs[128 * 32];
  const int tid = threadIdx.x;
  const int l = tid & 63, w = tid >> 6;
  const int lr = l & 15, lg = l >> 4;
  const int wm = w >> 1, wn = w & 1;
  const int mb = blockIdx.x / nblk, nb = blockIdx.x % nblk;
  const int r0 = mb * 128, c0 = nb * 128;
  const int prow = tid >> 2, pcol = (tid & 3) * 8;

  f32x4 acc[4][4];
#pragma unroll
  for (int mi = 0; mi < 4; ++mi)
#pragma unroll
    for (int ni = 0; ni < 4; ++ni) acc[mi][ni] = 0.0f;

  const size_t aoff0 = (size_t)(r0 + prow) * Kred + pcol;
  const size_t aoff1 = aoff0 + (size_t)64 * Kred;
  const size_t boff0 = (size_t)(c0 + prow) * Kred + pcol;
  const size_t boff1 = boff0 + (size_t)64 * Kred;

  const int nks = Kred >> 5;
  for (int ks = 0; ks < nks; ++ks) {
    const int k0 = ks * 32;
    gload_lds16(A + aoff0 + k0, &As[tid * 8]);
    gload_lds16(A + aoff1 + k0, &As[2048 + tid * 8]);
    gload_lds16(B + boff0 + k0, &Bs[tid * 8]);
    gload_lds16(B + boff1 + k0, &Bs[2048 + tid * 8]);
    __syncthreads();

    bf16x8 af[4], bfv[4];
#pragma unroll
    for (int mi = 0; mi < 4; ++mi)
      af[mi] = *reinterpret_cast<const bf16x8*>(
          &As[(wm * 64 + mi * 16 + lr) * 32 + lg * 8]);
#pragma unroll
    for (int ni = 0; ni < 4; ++ni)
      bfv[ni] = *reinterpret_cast<const bf16x8*>(
          &Bs[(wn * 64 + ni * 16 + lr) * 32 + lg * 8]);
#pragma unroll
    for (int mi = 0; mi < 4; ++mi)
#pragma unroll
      for (int ni = 0; ni < 4; ++ni)
        acc[mi][ni] = __builtin_amdgcn_mfma_f32_16x16x32_bf16(
            af[mi], bfv[ni], acc[mi][ni], 0, 0, 0);
    __syncthreads();
  }

#pragma unroll
  for (int ni = 0; ni < 4; ++ni) {
    const int col = c0 + wn * 64 + ni * 16 + lr;
    const float bv = bias[col];
#pragma unroll
    for (int mi = 0; mi < 4; ++mi) {
#pragma unroll
      for (int r = 0; r < 4; ++r) {
        const int row = r0 + wm * 64 + mi * 16 + lg * 4 + r;
        const float v = acc[mi][ni][r] + bv;
        if (EPI == 1) {
          ((unsigned short*)outp)[(size_t)row * Nsize + col] =
              f2bf(fmaxf(v, 0.0f));
        } else {
          ((float*)outp)[(size_t)row * Nsize + col] = v;
        }
      }
    }
  }
}

// ---------------------------------------------------------------------------
// K8: recon[row] = dec[idx[row]] gather-write + fused commitment loss.
// ---------------------------------------------------------------------------
__global__ __launch_bounds__(256) void epilogue_kernel(
    const float* __restrict__ x, const float* __restrict__ cb,
    const float* __restrict__ dec, const int* __restrict__ idx_ws,
    float* __restrict__ out) {
  __shared__ float wsum[4];
  const int r = blockIdx.x, t = threadIdx.x;
  const int code = idx_ws[r];
  const float4 dv = ((const float4*)(dec + (size_t)code * DDIM))[t];
  ((float4*)(out + (size_t)r * DDIM))[t] = dv;
  const float4 xv = ((const float4*)(x + (size_t)r * DDIM))[t];
  const float4 cv = ((const float4*)(cb + (size_t)code * DDIM))[t];
  const float ex = xv.x - cv.x, ey = xv.y - cv.y;
  const float ez = xv.z - cv.z, ew = xv.w - cv.w;
  float pr = ex * ex + ey * ey + ez * ez + ew * ew;
  pr = waveReduceSum(pr);
  if ((t & 63) == 0) wsum[t >> 6] = pr;
  __syncthreads();
  if (t == 0) {
    const float total = wsum[0] + wsum[1] + wsum[2] + wsum[3];
    atomicAdd(out + (size_t)MROWS * DDIM + MROWS, total * (0.25f / 16777216.0f));
  }
}

// ---------------------------------------------------------------------------
extern "C" void kernel_launch(void* const* d_in, const int* in_sizes, int n_in,
                              void* d_out, int out_size, void* d_ws,
                              size_t ws_size, hipStream_t stream) {
  const float* features = (const float*)d_in[0];  // [8,2048,1024]
  const float* codebook = (const float*)d_in[1];  // [8192,1024]
  const float* w1 = (const float*)d_in[2];        // [1024,512]
  const float* b1 = (const float*)d_in[3];        // [512]
  const float* w2 = (const float*)d_in[4];        // [512,1024]
  const float* b2 = (const float*)d_in[5];        // [1024]
  float* out = (float*)d_out;
  char* ws = (char*)d_ws;

  unsigned short* xb  = (unsigned short*)(ws + 0);         // 33,554,432
  unsigned short* cbb = (unsigned short*)(ws + 33554432);  // 16,777,216
  float*          cn  = (float*)(ws + 50331648);           //     32,768
  unsigned short* w1t = (unsigned short*)(ws + 50364416);  //  1,048,576
  unsigned short* w2t = (unsigned short*)(ws + 51412992);  //  1,048,576
  unsigned short* hb  = (unsigned short*)(ws + 52461568);  //  8,388,608
  float*          dec = (float*)(ws + 60850176);           // 33,554,432
  uint32_t*       cand = (uint32_t*)(ws + 94404608);       //  1,048,576
  int*            idxw = (int*)(ws + 95453184);            //     65,536
  // cand2 (16 MB) aliases dec: consumed by merge_kernel BEFORE gemm<2>
  // writes dec (stream-ordered -> safe).
  uint32_t*       cand2 = (uint32_t*)(ws + 60850176);

  cvt_x_kernel<<<16384, 256, 0, stream>>>(features, xb, MROWS * DDIM / 4);
  cvt_cb_cn_kernel<<<KCODES, 256, 0, stream>>>(codebook, cbb, cn);
  transpose_w_kernel<<<2048, 256, 0, stream>>>(w1, w1t, DDIM, HDIM);
  transpose_w_kernel<<<2048, 256, 0, stream>>>(w2, w2t, HDIM, DDIM);

  coarse_kernel<<<(MROWS / 256) * (KCODES / 128), 256, 0, stream>>>(
      xb, cbb, cn, cand2);
  merge_kernel<<<MROWS / 4, 256, 0, stream>>>(cand2, cand);
  rescore_kernel<<<MROWS, 64, 0, stream>>>(features, codebook, cand, idxw, out);

  // decode the codebook (8192 rows), then recon = dec[idx]
  gemm_bt_kernel<1><<<64 * (HDIM / 128), 256, 0, stream>>>(
      cbb, w1t, b1, hb, HDIM, DDIM, HDIM / 128);
  gemm_bt_kernel<2><<<64 * (DDIM / 128), 256, 0, stream>>>(
      hb, w2t, b2, dec, DDIM, HDIM, DDIM / 128);

  epilogue_kernel<<<MROWS, 256, 0, stream>>>(features, codebook, dec, idxw, out);
}